// Round 3
// baseline (421.747 us; speedup 1.0000x reference)
//
#include <hip/hip_runtime.h>

// FeatureExtractor via MFMA bf16 hi/lo, TRANSPOSED orientation,
// PRODUCER/CONSUMER wave specialization (2 waves/block, 2 waves/SIMD).
//   wave 0 (producer): gx(t+1) = Wih*p(t+1)+bih  (x load/split, proj MFMA,
//       LeakyReLU, p LDS exchange, 18 ih-MFMAs) -> LDS ring slot (t+1)&1
//   wave 1 (consumer): gru_step(t): h LDS read/split, 18 hh-MFMAs seeded
//       from gx slot t&1, nonlinearity, h write.
// One __syncthreads per step, alternating slots. Step time = max(halves)
// instead of sum, and 2 waves/SIMD fill each other's issue stalls.
// Numerics bit-identical to R2: producer is exactly R2's compute_gx (same
// MFMA order); consumer seeds acc = gx then the same 3-term hh chains.
//
// Weight fragments overlaid by role (producer: Wih in Wg, W1 in Wp;
// consumer: Whh in Wg) so VGPR stays well under the 2-waves/SIMD cap.
// gx slot layout [slot][gate][tile][q][m] as f32x4: the wave's 64 lanes
// (q,m) touch a contiguous 1KB span -> conflict-free b128 LDS access.
//
// Layouts per verified guide mapping: A[m][k]/B[k][n]: m|n=lane&15,
// k=(lane>>4)*8+j; D: col=lane&15, row=(lane>>4)*4+reg.

typedef __bf16 bf16x8 __attribute__((ext_vector_type(8)));
typedef float  f32x4  __attribute__((ext_vector_type(4)));

#define TT 128
#define CC 25
#define PP 20
#define HH 25
#define NSEQ 16384
#define S  36          // LDS row stride (floats) for sp/sh
#define MFMA __builtin_amdgcn_mfma_f32_16x16x32_bf16

__device__ __forceinline__ void split2(float f, __bf16& hi, __bf16& lo) {
    hi = (__bf16)f;
    lo = (__bf16)(f - (float)hi);
}
__device__ __forceinline__ float sigm(float v) { return 1.f / (1.f + __expf(-v)); }

__global__ __launch_bounds__(128, 2) void gru_pc(
    const float* __restrict__ x,   const float* __restrict__ W1,
    const float* __restrict__ b1,  const float* __restrict__ Wih,
    const float* __restrict__ Whh, const float* __restrict__ bih,
    const float* __restrict__ bhh, float* __restrict__ out)
{
    __shared__ float sp[16 * S];            // producer: p rows, ch20 = 1.0
    __shared__ float sh[2][16 * S];         // consumer: h rows, ch25 = 1.0
    __shared__ f32x4 sgx[2][3][2][4][16];   // [slot][gate r/z/n][tile][q][m]

    const int tid  = threadIdx.x;
    const int wid  = tid >> 6;              // 0 = producer, 1 = consumer
    const bool pw  = (wid == 0);
    const int lane = tid & 63;
    const int m = lane & 15, q = lane >> 4;
    const int n0 = blockIdx.x * 16;

    // ---- LDS init: zeros + bias channels ----
    for (int idx = tid; idx < 16 * S; idx += 128) {
        sp[idx] = 0.f; sh[0][idx] = 0.f; sh[1][idx] = 0.f;
    }
    __syncthreads();
    if (tid < 16) {
        sp[tid * S + PP]    = 1.0f;
        sh[0][tid * S + HH] = 1.0f;
        sh[1][tid * S + HH] = 1.0f;
    }
    __syncthreads();

    // ---- gate weight A-fragments, overlaid by role ----
    // producer: Wg = Wih hi/lo (k-dim PP, bias at k==PP)
    // consumer: Wg = Whh hi/lo (k-dim HH, bias at k==HH)
    bf16x8 WgH[6], WgL[6], WpH[2], WpL[2];
    {
        const float* Ws = pw ? Wih : Whh;
        const float* bs = pw ? bih : bhh;
        const int kd    = pw ? PP  : HH;
        #pragma unroll
        for (int tt = 0; tt < 6; ++tt) {
            const int g = tt >> 1;                 // 0=r,1=z,2=n
            const int u = (tt & 1) * 16 + m;       // unit within gate
            const bool uv = (u < HH);
            const int row = g * HH + u;
            bf16x8 h8, l8;
            #pragma unroll
            for (int j = 0; j < 8; ++j) {
                const int k = q * 8 + j;
                float v = 0.f;
                if (uv) {
                    if (k < kd)       v = Ws[row * kd + k];
                    else if (k == kd) v = bs[row];
                }
                __bf16 a, b; split2(v, a, b); h8[j] = a; l8[j] = b;
            }
            WgH[tt] = h8; WgL[tt] = l8;
        }
    }
    if (pw) {
        #pragma unroll
        for (int tt = 0; tt < 2; ++tt) {
            const int u = tt * 16 + m;
            const bool uv = (u < PP);
            bf16x8 h8, l8;
            #pragma unroll
            for (int j = 0; j < 8; ++j) {
                const int k = q * 8 + j;
                float v = 0.f;
                if (uv) {
                    if (k < CC)       v = W1[u * CC + k];
                    else if (k == CC) v = b1[u];
                }
                __bf16 a, b; split2(v, a, b); h8[j] = a; l8[j] = b;
            }
            WpH[tt] = h8; WpL[tt] = l8;
        }
    }

    // ---- producer state ----
    const float* xrow = x + (size_t)(n0 + m) * (TT * CC);
    float xc[8];

    // produce gx(tc) from xc (== x(tc)); prefetch x(tc+1) into xc
    auto produce = [&](int tc) {
        bf16x8 xH, xL;
        #pragma unroll
        for (int j = 0; j < 8; ++j) { __bf16 a,b; split2(xc[j],a,b); xH[j]=a; xL[j]=b; }

        {   // guarded prefetch (bias/0 slots retained); in flight across the step
            const int tn = (tc + 1 < TT) ? tc + 1 : TT - 1;
            const float* xr = xrow + tn * CC;
            #pragma unroll
            for (int j = 0; j < 8; ++j) {
                const int k = q * 8 + j;
                if (k < CC) xc[j] = xr[k];
            }
        }

        // proj: P[unit][seq] = W1aug * [x;1]  (3-term hi/lo)
        f32x4 p0 = {0.f,0.f,0.f,0.f}, p1 = {0.f,0.f,0.f,0.f};
        p0 = MFMA(WpH[0], xH, p0, 0,0,0);
        p0 = MFMA(WpH[0], xL, p0, 0,0,0);
        p0 = MFMA(WpL[0], xH, p0, 0,0,0);
        p1 = MFMA(WpH[1], xH, p1, 0,0,0);
        p1 = MFMA(WpH[1], xL, p1, 0,0,0);
        p1 = MFMA(WpL[1], xH, p1, 0,0,0);
        #pragma unroll
        for (int r = 0; r < 4; ++r) {
            p0[r] = (p0[r] >= 0.f) ? p0[r] : 0.01f * p0[r];
            p1[r] = (p1[r] >= 0.f) ? p1[r] : 0.01f * p1[r];
        }

        // p -> LDS exchange (in-wave, barrier-free; same guards as R2)
        *(f32x4*)(sp + m * S + 4 * q) = p0;
        if (q == 0) *(f32x4*)(sp + m * S + 16) = p1;

        f32x4 pa = ((const f32x4*)(sp + m * S + 8 * q))[0];
        f32x4 pb = ((const f32x4*)(sp + m * S + 8 * q))[1];
        bf16x8 pH, pL;
        #pragma unroll
        for (int j = 0; j < 4; ++j) {
            __bf16 a, b;
            split2(pa[j], a, b); pH[j]   = a; pL[j]   = b;
            split2(pb[j], a, b); pH[4+j] = a; pL[4+j] = b;
        }

        // ih gate pre-activations (zero-init; same 3-term order as R2)
        const int s = tc & 1;
        #pragma unroll
        for (int tp = 0; tp < 2; ++tp) {
            f32x4 acc = {0.f,0.f,0.f,0.f};
            acc = MFMA(WgH[tp], pH, acc, 0,0,0);
            acc = MFMA(WgH[tp], pL, acc, 0,0,0);
            acc = MFMA(WgL[tp], pH, acc, 0,0,0);
            sgx[s][0][tp][q][m] = acc;
            f32x4 az = {0.f,0.f,0.f,0.f};
            az = MFMA(WgH[2+tp], pH, az, 0,0,0);
            az = MFMA(WgH[2+tp], pL, az, 0,0,0);
            az = MFMA(WgL[2+tp], pH, az, 0,0,0);
            sgx[s][1][tp][q][m] = az;
            f32x4 an = {0.f,0.f,0.f,0.f};
            an = MFMA(WgH[4+tp], pH, an, 0,0,0);
            an = MFMA(WgH[4+tp], pL, an, 0,0,0);
            an = MFMA(WgL[4+tp], pH, an, 0,0,0);
            sgx[s][2][tp][q][m] = an;
        }
    };

    // ---- consumer state ----
    float ho[2][4] = {{0.f,0.f,0.f,0.f},{0.f,0.f,0.f,0.f}};

    auto consume = [&](int t) {
        const float* hrow = sh[t & 1] + m * S + 8 * q;
        f32x4 ha = ((const f32x4*)hrow)[0];
        f32x4 hb = ((const f32x4*)hrow)[1];
        bf16x8 hH, hL;
        #pragma unroll
        for (int j = 0; j < 4; ++j) {
            __bf16 a, b;
            split2(ha[j], a, b); hH[j]   = a; hL[j]   = b;
            split2(hb[j], a, b); hH[4+j] = a; hL[4+j] = b;
        }
        const int s = t & 1;
        f32x4 aR[2], aZ[2], aHn[2], gN[2];
        #pragma unroll
        for (int tp = 0; tp < 2; ++tp) {
            f32x4 acc = sgx[s][0][tp][q][m];          // = ih terms, same order
            acc = MFMA(WgH[tp], hH, acc, 0,0,0);
            acc = MFMA(WgH[tp], hL, acc, 0,0,0);
            acc = MFMA(WgL[tp], hH, acc, 0,0,0);
            aR[tp] = acc;
            f32x4 az = sgx[s][1][tp][q][m];
            az = MFMA(WgH[2+tp], hH, az, 0,0,0);
            az = MFMA(WgH[2+tp], hL, az, 0,0,0);
            az = MFMA(WgL[2+tp], hH, az, 0,0,0);
            aZ[tp] = az;
            gN[tp] = sgx[s][2][tp][q][m];
            f32x4 ah = {0.f,0.f,0.f,0.f};
            ah = MFMA(WgH[4+tp], hH, ah, 0,0,0);
            ah = MFMA(WgH[4+tp], hL, ah, 0,0,0);
            ah = MFMA(WgL[4+tp], hH, ah, 0,0,0);
            aHn[tp] = ah;
        }
        // nonlinearity + h update + store to next buffer (same guards as R2)
        #pragma unroll
        for (int tp = 0; tp < 2; ++tp) {
            f32x4 hv;
            #pragma unroll
            for (int r = 0; r < 4; ++r) {
                const float rg = sigm(aR[tp][r]);
                const float zg = sigm(aZ[tp][r]);
                const float nv = gN[tp][r] + rg * aHn[tp][r];
                const float e  = __expf(-2.f * nv);
                const float ng = 2.f / (1.f + e) - 1.f;          // tanh
                const float h2 = zg * (ho[tp][r] - ng) + ng;     // (1-z)n + z h
                ho[tp][r] = h2; hv[r] = h2;
            }
            float* dst = sh[(t + 1) & 1] + m * S + tp * 16 + 4 * q;
            if (tp == 0) {
                *(f32x4*)dst = hv;
            } else {
                if (q < 2)       *(f32x4*)dst = hv;     // units 16-23
                else if (q == 2) dst[0] = hv[0];        // unit 24 (25-27 stay pad)
            }
        }
    };

    // ---- prologue: producer fills gx(0) ----
    if (pw) {
        #pragma unroll
        for (int j = 0; j < 8; ++j) {
            const int k = q * 8 + j;
            xc[j] = (k < CC) ? xrow[k] : (k == CC ? 1.0f : 0.f);
        }
        produce(0);                 // gx(0) -> slot 0; prefetch x(1)
    }
    __syncthreads();

    // ---- lockstep loop: producer one step ahead ----
    for (int t = 0; t < TT; ++t) {
        if (pw) {
            if (t + 1 < TT) produce(t + 1);   // gx(t+1) -> slot (t+1)&1
        } else {
            consume(t);                        // reads slot t&1
        }
        __syncthreads();
    }

    // ---- epilogue: consumer writes out[seq][unit] ----
    if (!pw) {
        float* orow = out + (size_t)(n0 + m) * HH;
        #pragma unroll
        for (int tp = 0; tp < 2; ++tp) {
            #pragma unroll
            for (int r = 0; r < 4; ++r) {
                const int u = tp * 16 + 4 * q + r;
                if (u < HH) orow[u] = ho[tp][r];
            }
        }
    }
}

extern "C" void kernel_launch(void* const* d_in, const int* in_sizes, int n_in,
                              void* d_out, int out_size, void* d_ws, size_t ws_size,
                              hipStream_t stream) {
    const float* x   = (const float*)d_in[0];
    const float* W1  = (const float*)d_in[1];
    const float* b1  = (const float*)d_in[2];
    const float* Wih = (const float*)d_in[3];
    const float* Whh = (const float*)d_in[4];
    const float* bih = (const float*)d_in[5];
    const float* bhh = (const float*)d_in[6];
    float* out = (float*)d_out;

    gru_pc<<<NSEQ / 16, 128, 0, stream>>>(x, W1, b1, Wih, Whh, bih, bhh, out);
}

// Round 4
// 395.217 us; speedup vs baseline: 1.0671x; 1.0671x over previous
//
#include <hip/hip_runtime.h>

// FeatureExtractor via MFMA bf16 hi/lo, TRANSPOSED orientation,
// DECOUPLED producer/consumer (2 waves/block), depth-4 LDS gx ring,
// monotone sequence counters instead of per-step __syncthreads.
//   wave 0 (producer): gx(t) = Wih*p(t)+bih  (vectorized x load, proj MFMA,
//       LeakyReLU, p LDS exchange, 18 ih-MFMAs) -> ring slot t&3; runs up to
//       4 steps ahead, so its HBM latency / LDS round-trips amortize.
//   wave 1 (consumer): gru_step(t): h LDS read/split, 18 hh-MFMAs seeded
//       from ring slot t&3, nonlinearity, h write. No barrier, no vmcnt
//       drain: steady-state step cost = consumer's own chain only.
// Handshake: s_prod/s_cons monotone ints in LDS, release-store by lane 0,
// acquire-load polls cached in a local 'known' so the fast path does zero
// LDS reads. Producer waits only if 4 ahead; consumer only if 0 ahead.
// Numerics bit-identical to R2/R3 (same MFMA order everywhere).
//
// Layouts per verified guide mapping: A[m][k]/B[k][n]: m|n=lane&15,
// k=(lane>>4)*8+j; D: col=lane&15, row=(lane>>4)*4+reg.

typedef __bf16 bf16x8 __attribute__((ext_vector_type(8)));
typedef float  f32x4  __attribute__((ext_vector_type(4)));

#define TT 128
#define CC 25
#define PP 20
#define HH 25
#define NSEQ 16384
#define S  36          // LDS row stride (floats) for sp/sh
#define MFMA __builtin_amdgcn_mfma_f32_16x16x32_bf16
#define LD_ACQ(p)    __hip_atomic_load((p), __ATOMIC_ACQUIRE, __HIP_MEMORY_SCOPE_WORKGROUP)
#define ST_REL(p, v) __hip_atomic_store((p), (v), __ATOMIC_RELEASE, __HIP_MEMORY_SCOPE_WORKGROUP)

__device__ __forceinline__ void split2(float f, __bf16& hi, __bf16& lo) {
    hi = (__bf16)f;
    lo = (__bf16)(f - (float)hi);
}
__device__ __forceinline__ float sigm(float v) { return 1.f / (1.f + __expf(-v)); }

__global__ __launch_bounds__(128, 2) void gru_ring(
    const float* __restrict__ x,   const float* __restrict__ W1,
    const float* __restrict__ b1,  const float* __restrict__ Wih,
    const float* __restrict__ Whh, const float* __restrict__ bih,
    const float* __restrict__ bhh, float* __restrict__ out)
{
    __shared__ float sp[16 * S];            // producer: p rows, ch20 = 1.0
    __shared__ float sh[2][16 * S];         // consumer: h rows, ch25 = 1.0
    __shared__ f32x4 sgx[4][3][2][4][16];   // ring [slot][gate][tile][q][m]
    __shared__ int s_prod, s_cons;          // monotone step counters

    const int tid  = threadIdx.x;
    const bool pw  = (tid < 64);            // wave 0 = producer
    const int lane = tid & 63;
    const int m = lane & 15, q = lane >> 4;
    const int n0 = blockIdx.x * 16;

    // ---- LDS init: zeros + bias channels + flags ----
    for (int idx = tid; idx < 16 * S; idx += 128) {
        sp[idx] = 0.f; sh[0][idx] = 0.f; sh[1][idx] = 0.f;
    }
    if (tid == 0) { s_prod = 0; s_cons = 0; }
    __syncthreads();
    if (tid < 16) {
        sp[tid * S + PP]    = 1.0f;
        sh[0][tid * S + HH] = 1.0f;
        sh[1][tid * S + HH] = 1.0f;
    }
    __syncthreads();

    // ---- gate weight A-fragments, overlaid by role ----
    bf16x8 WgH[6], WgL[6], WpH[2], WpL[2];
    {
        const float* Ws = pw ? Wih : Whh;
        const float* bs = pw ? bih : bhh;
        const int kd    = pw ? PP  : HH;
        #pragma unroll
        for (int tt = 0; tt < 6; ++tt) {
            const int g = tt >> 1;                 // 0=r,1=z,2=n
            const int u = (tt & 1) * 16 + m;       // unit within gate
            const bool uv = (u < HH);
            const int row = g * HH + u;
            bf16x8 h8, l8;
            #pragma unroll
            for (int j = 0; j < 8; ++j) {
                const int k = q * 8 + j;
                float v = 0.f;
                if (uv) {
                    if (k < kd)       v = Ws[row * kd + k];
                    else if (k == kd) v = bs[row];
                }
                __bf16 a, b; split2(v, a, b); h8[j] = a; l8[j] = b;
            }
            WgH[tt] = h8; WgL[tt] = l8;
        }
    }
    if (pw) {
        #pragma unroll
        for (int tt = 0; tt < 2; ++tt) {
            const int u = tt * 16 + m;
            const bool uv = (u < PP);
            bf16x8 h8, l8;
            #pragma unroll
            for (int j = 0; j < 8; ++j) {
                const int k = q * 8 + j;
                float v = 0.f;
                if (uv) {
                    if (k < CC)       v = W1[u * CC + k];
                    else if (k == CC) v = b1[u];
                }
                __bf16 a, b; split2(v, a, b); h8[j] = a; l8[j] = b;
            }
            WpH[tt] = h8; WpL[tt] = l8;
        }
    }

    if (pw) {
        // ================= PRODUCER =================
        const float* xrow = x + (size_t)(n0 + m) * (TT * CC);
        // lane wants channels q*8..q*8+7 of a 25-float row: two dwordx4
        // (q==3: one backward-shifted dwordx4 at c=21..24, elem 3 = c24).
        const int cbase = (q < 3) ? q * 8 : 21;
        float xc[8];

        auto load_x = [&](int t) {
            const float* xr = xrow + t * CC;
            f32x4 va = *(const f32x4*)(xr + cbase);
            f32x4 vb = *(const f32x4*)(xr + cbase + ((q < 3) ? 4 : 0));
            #pragma unroll
            for (int j = 0; j < 8; ++j) {
                float v;
                if (q < 3) v = (j < 4) ? va[j] : vb[j - 4];
                else       v = (j == 0) ? va[3] : (j == 1 ? 1.0f : 0.0f);
                xc[j] = v;
            }
        };

        auto produce = [&](int tc) {
            bf16x8 xH, xL;
            #pragma unroll
            for (int j = 0; j < 8; ++j) { __bf16 a,b; split2(xc[j],a,b); xH[j]=a; xL[j]=b; }

            {   // prefetch next x; in flight across the rest of this step
                const int tn = (tc + 1 < TT) ? tc + 1 : TT - 1;
                load_x(tn);
            }

            // proj: P[unit][seq] = W1aug * [x;1]  (3-term hi/lo, same order)
            f32x4 p0 = {0.f,0.f,0.f,0.f}, p1 = {0.f,0.f,0.f,0.f};
            p0 = MFMA(WpH[0], xH, p0, 0,0,0);
            p0 = MFMA(WpH[0], xL, p0, 0,0,0);
            p0 = MFMA(WpL[0], xH, p0, 0,0,0);
            p1 = MFMA(WpH[1], xH, p1, 0,0,0);
            p1 = MFMA(WpH[1], xL, p1, 0,0,0);
            p1 = MFMA(WpL[1], xH, p1, 0,0,0);
            #pragma unroll
            for (int r = 0; r < 4; ++r) {
                p0[r] = (p0[r] >= 0.f) ? p0[r] : 0.01f * p0[r];
                p1[r] = (p1[r] >= 0.f) ? p1[r] : 0.01f * p1[r];
            }

            // p -> LDS exchange (in-wave, producer-private)
            *(f32x4*)(sp + m * S + 4 * q) = p0;
            if (q == 0) *(f32x4*)(sp + m * S + 16) = p1;

            f32x4 pa = ((const f32x4*)(sp + m * S + 8 * q))[0];
            f32x4 pb = ((const f32x4*)(sp + m * S + 8 * q))[1];
            bf16x8 pH, pL;
            #pragma unroll
            for (int j = 0; j < 4; ++j) {
                __bf16 a, b;
                split2(pa[j], a, b); pH[j]   = a; pL[j]   = b;
                split2(pb[j], a, b); pH[4+j] = a; pL[4+j] = b;
            }

            // ih gate pre-activations -> ring slot (zero-init; same order)
            const int s = tc & 3;
            #pragma unroll
            for (int tp = 0; tp < 2; ++tp) {
                f32x4 acc = {0.f,0.f,0.f,0.f};
                acc = MFMA(WgH[tp], pH, acc, 0,0,0);
                acc = MFMA(WgH[tp], pL, acc, 0,0,0);
                acc = MFMA(WgL[tp], pH, acc, 0,0,0);
                sgx[s][0][tp][q][m] = acc;
                f32x4 az = {0.f,0.f,0.f,0.f};
                az = MFMA(WgH[2+tp], pH, az, 0,0,0);
                az = MFMA(WgH[2+tp], pL, az, 0,0,0);
                az = MFMA(WgL[2+tp], pH, az, 0,0,0);
                sgx[s][1][tp][q][m] = az;
                f32x4 an = {0.f,0.f,0.f,0.f};
                an = MFMA(WgH[4+tp], pH, an, 0,0,0);
                an = MFMA(WgH[4+tp], pL, an, 0,0,0);
                an = MFMA(WgL[4+tp], pH, an, 0,0,0);
                sgx[s][2][tp][q][m] = an;
            }
        };

        load_x(0);
        int known_cons = 0;
        for (int t = 0; t < TT; ++t) {
            // slot t&3 was consumed at step t-4 -> need s_cons >= t-3
            if (t >= 4 && known_cons < t - 3) {
                do { known_cons = LD_ACQ(&s_cons); } while (known_cons < t - 3);
            }
            produce(t);
            if (lane == 0) ST_REL(&s_prod, t + 1);
        }
    } else {
        // ================= CONSUMER =================
        float ho[2][4] = {{0.f,0.f,0.f,0.f},{0.f,0.f,0.f,0.f}};
        int known_prod = 0;

        for (int t = 0; t < TT; ++t) {
            if (known_prod < t + 1) {
                do { known_prod = LD_ACQ(&s_prod); } while (known_prod < t + 1);
            }

            const float* hrow = sh[t & 1] + m * S + 8 * q;
            f32x4 ha = ((const f32x4*)hrow)[0];
            f32x4 hb = ((const f32x4*)hrow)[1];
            bf16x8 hH, hL;
            #pragma unroll
            for (int j = 0; j < 4; ++j) {
                __bf16 a, b;
                split2(ha[j], a, b); hH[j]   = a; hL[j]   = b;
                split2(hb[j], a, b); hH[4+j] = a; hL[4+j] = b;
            }
            const int s = t & 3;
            f32x4 aR[2], aZ[2], aHn[2], gN[2];
            #pragma unroll
            for (int tp = 0; tp < 2; ++tp) {
                f32x4 acc = sgx[s][0][tp][q][m];          // = ih terms
                acc = MFMA(WgH[tp], hH, acc, 0,0,0);
                acc = MFMA(WgH[tp], hL, acc, 0,0,0);
                acc = MFMA(WgL[tp], hH, acc, 0,0,0);
                aR[tp] = acc;
                f32x4 az = sgx[s][1][tp][q][m];
                az = MFMA(WgH[2+tp], hH, az, 0,0,0);
                az = MFMA(WgH[2+tp], hL, az, 0,0,0);
                az = MFMA(WgL[2+tp], hH, az, 0,0,0);
                aZ[tp] = az;
                gN[tp] = sgx[s][2][tp][q][m];
                f32x4 ah = {0.f,0.f,0.f,0.f};
                ah = MFMA(WgH[4+tp], hH, ah, 0,0,0);
                ah = MFMA(WgH[4+tp], hL, ah, 0,0,0);
                ah = MFMA(WgL[4+tp], hH, ah, 0,0,0);
                aHn[tp] = ah;
            }
            // nonlinearity + h update + store to next buffer (same guards)
            #pragma unroll
            for (int tp = 0; tp < 2; ++tp) {
                f32x4 hv;
                #pragma unroll
                for (int r = 0; r < 4; ++r) {
                    const float rg = sigm(aR[tp][r]);
                    const float zg = sigm(aZ[tp][r]);
                    const float nv = gN[tp][r] + rg * aHn[tp][r];
                    const float e  = __expf(-2.f * nv);
                    const float ng = 2.f / (1.f + e) - 1.f;          // tanh
                    const float h2 = zg * (ho[tp][r] - ng) + ng;     // (1-z)n + z h
                    ho[tp][r] = h2; hv[r] = h2;
                }
                float* dst = sh[(t + 1) & 1] + m * S + tp * 16 + 4 * q;
                if (tp == 0) {
                    *(f32x4*)dst = hv;
                } else {
                    if (q < 2)       *(f32x4*)dst = hv;     // units 16-23
                    else if (q == 2) dst[0] = hv[0];        // unit 24
                }
            }
            if (lane == 0) ST_REL(&s_cons, t + 1);
        }

        // ---- epilogue: out[seq][unit] ----
        float* orow = out + (size_t)(n0 + m) * HH;
        #pragma unroll
        for (int tp = 0; tp < 2; ++tp) {
            #pragma unroll
            for (int r = 0; r < 4; ++r) {
                const int u = tp * 16 + 4 * q + r;
                if (u < HH) orow[u] = ho[tp][r];
            }
        }
    }
}

extern "C" void kernel_launch(void* const* d_in, const int* in_sizes, int n_in,
                              void* d_out, int out_size, void* d_ws, size_t ws_size,
                              hipStream_t stream) {
    const float* x   = (const float*)d_in[0];
    const float* W1  = (const float*)d_in[1];
    const float* b1  = (const float*)d_in[2];
    const float* Wih = (const float*)d_in[3];
    const float* Whh = (const float*)d_in[4];
    const float* bih = (const float*)d_in[5];
    const float* bhh = (const float*)d_in[6];
    float* out = (float*)d_out;

    gru_ring<<<NSEQ / 16, 128, 0, stream>>>(x, W1, b1, Wih, Whh, bih, bhh, out);
}

// Round 5
// 358.458 us; speedup vs baseline: 1.1766x; 1.1025x over previous
//
#include <hip/hip_runtime.h>

// FeatureExtractor via MFMA bf16 hi/lo, TRANSPOSED orientation,
// DECOUPLED producer/consumer (2 waves/block), depth-4 LDS gx ring.
// R5 changes vs R4 (issue-bound: VALUBusy+MfmaUtil ~84%):
//  1. all f32 divides (2 sigmoids + tanh per element = 24/step) replaced by
//     __builtin_amdgcn_rcpf: 1 v_rcp instead of the ~9-instr correctly-rounded
//     div sequence (no -ffast-math in harness). ~1ulp, invisible at our absmax.
//  2. role loops unrolled x4: ring slot t&3 and h parity t&1 become
//     compile-time -> LDS addressing folds to base+immediate.
//  3. gx ring re-laid out as [slot][lane][6 x f32x4]: one base register per
//     step + offset:0..80 immediates for all 6 writes/reads.
// Ring protocol, MFMA order, hi/lo splits, handshake: identical to R4.
//
// Layouts per verified guide mapping: A[m][k]/B[k][n]: m|n=lane&15,
// k=(lane>>4)*8+j; D: col=lane&15, row=(lane>>4)*4+reg.

typedef __bf16 bf16x8 __attribute__((ext_vector_type(8)));
typedef float  f32x4  __attribute__((ext_vector_type(4)));

#define TT 128
#define CC 25
#define PP 20
#define HH 25
#define NSEQ 16384
#define S  36          // LDS row stride (floats) for sp/sh
#define MFMA __builtin_amdgcn_mfma_f32_16x16x32_bf16
#define LD_ACQ(p)    __hip_atomic_load((p), __ATOMIC_ACQUIRE, __HIP_MEMORY_SCOPE_WORKGROUP)
#define ST_REL(p, v) __hip_atomic_store((p), (v), __ATOMIC_RELEASE, __HIP_MEMORY_SCOPE_WORKGROUP)

__device__ __forceinline__ void split2(float f, __bf16& hi, __bf16& lo) {
    hi = (__bf16)f;
    lo = (__bf16)(f - (float)hi);
}
__device__ __forceinline__ float frcp(float v) { return __builtin_amdgcn_rcpf(v); }

__global__ __launch_bounds__(128, 2) void gru_ring(
    const float* __restrict__ x,   const float* __restrict__ W1,
    const float* __restrict__ b1,  const float* __restrict__ Wih,
    const float* __restrict__ Whh, const float* __restrict__ bih,
    const float* __restrict__ bhh, float* __restrict__ out)
{
    __shared__ float sp[16 * S];            // producer: p rows, ch20 = 1.0
    __shared__ float sh[2][16 * S];         // consumer: h rows, ch25 = 1.0
    __shared__ f32x4 sgx[4][64][6];         // ring [slot][lane][gate*2+tile]
    __shared__ int s_prod, s_cons;          // monotone step counters

    const int tid  = threadIdx.x;
    const bool pw  = (tid < 64);            // wave 0 = producer
    const int lane = tid & 63;
    const int m = lane & 15, q = lane >> 4;
    const int n0 = blockIdx.x * 16;

    // ---- LDS init: zeros + bias channels + flags ----
    for (int idx = tid; idx < 16 * S; idx += 128) {
        sp[idx] = 0.f; sh[0][idx] = 0.f; sh[1][idx] = 0.f;
    }
    if (tid == 0) { s_prod = 0; s_cons = 0; }
    __syncthreads();
    if (tid < 16) {
        sp[tid * S + PP]    = 1.0f;
        sh[0][tid * S + HH] = 1.0f;
        sh[1][tid * S + HH] = 1.0f;
    }
    __syncthreads();

    // ---- gate weight A-fragments, overlaid by role ----
    bf16x8 WgH[6], WgL[6], WpH[2], WpL[2];
    {
        const float* Ws = pw ? Wih : Whh;
        const float* bs = pw ? bih : bhh;
        const int kd    = pw ? PP  : HH;
        #pragma unroll
        for (int tt = 0; tt < 6; ++tt) {
            const int g = tt >> 1;                 // 0=r,1=z,2=n
            const int u = (tt & 1) * 16 + m;       // unit within gate
            const bool uv = (u < HH);
            const int row = g * HH + u;
            bf16x8 h8, l8;
            #pragma unroll
            for (int j = 0; j < 8; ++j) {
                const int k = q * 8 + j;
                float v = 0.f;
                if (uv) {
                    if (k < kd)       v = Ws[row * kd + k];
                    else if (k == kd) v = bs[row];
                }
                __bf16 a, b; split2(v, a, b); h8[j] = a; l8[j] = b;
            }
            WgH[tt] = h8; WgL[tt] = l8;
        }
    }
    if (pw) {
        #pragma unroll
        for (int tt = 0; tt < 2; ++tt) {
            const int u = tt * 16 + m;
            const bool uv = (u < PP);
            bf16x8 h8, l8;
            #pragma unroll
            for (int j = 0; j < 8; ++j) {
                const int k = q * 8 + j;
                float v = 0.f;
                if (uv) {
                    if (k < CC)       v = W1[u * CC + k];
                    else if (k == CC) v = b1[u];
                }
                __bf16 a, b; split2(v, a, b); h8[j] = a; l8[j] = b;
            }
            WpH[tt] = h8; WpL[tt] = l8;
        }
    }

    if (pw) {
        // ================= PRODUCER =================
        const float* xrow = x + (size_t)(n0 + m) * (TT * CC);
        // lane wants channels q*8..q*8+7 of a 25-float row: two dwordx4
        // (q==3: one backward-shifted dwordx4 at c=21..24, elem 3 = c24).
        const int cbase = (q < 3) ? q * 8 : 21;
        float xc[8];

        auto load_x = [&](int t) {
            const float* xr = xrow + t * CC;
            f32x4 va = *(const f32x4*)(xr + cbase);
            f32x4 vb = *(const f32x4*)(xr + cbase + ((q < 3) ? 4 : 0));
            #pragma unroll
            for (int j = 0; j < 8; ++j) {
                float v;
                if (q < 3) v = (j < 4) ? va[j] : vb[j - 4];
                else       v = (j == 0) ? va[3] : (j == 1 ? 1.0f : 0.0f);
                xc[j] = v;
            }
        };

        auto produce = [&](int tc, int slot) {      // slot == tc&3, literal
            bf16x8 xH, xL;
            #pragma unroll
            for (int j = 0; j < 8; ++j) { __bf16 a,b; split2(xc[j],a,b); xH[j]=a; xL[j]=b; }

            {   // prefetch next x; in flight across the rest of this step
                const int tn = (tc + 1 < TT) ? tc + 1 : TT - 1;
                load_x(tn);
            }

            // proj: P[unit][seq] = W1aug * [x;1]  (3-term hi/lo, same order)
            f32x4 p0 = {0.f,0.f,0.f,0.f}, p1 = {0.f,0.f,0.f,0.f};
            p0 = MFMA(WpH[0], xH, p0, 0,0,0);
            p0 = MFMA(WpH[0], xL, p0, 0,0,0);
            p0 = MFMA(WpL[0], xH, p0, 0,0,0);
            p1 = MFMA(WpH[1], xH, p1, 0,0,0);
            p1 = MFMA(WpH[1], xL, p1, 0,0,0);
            p1 = MFMA(WpL[1], xH, p1, 0,0,0);
            #pragma unroll
            for (int r = 0; r < 4; ++r) {
                p0[r] = (p0[r] >= 0.f) ? p0[r] : 0.01f * p0[r];
                p1[r] = (p1[r] >= 0.f) ? p1[r] : 0.01f * p1[r];
            }

            // p -> LDS exchange (in-wave, producer-private)
            *(f32x4*)(sp + m * S + 4 * q) = p0;
            if (q == 0) *(f32x4*)(sp + m * S + 16) = p1;

            f32x4 pa = ((const f32x4*)(sp + m * S + 8 * q))[0];
            f32x4 pb = ((const f32x4*)(sp + m * S + 8 * q))[1];
            bf16x8 pH, pL;
            #pragma unroll
            for (int j = 0; j < 4; ++j) {
                __bf16 a, b;
                split2(pa[j], a, b); pH[j]   = a; pL[j]   = b;
                split2(pb[j], a, b); pH[4+j] = a; pL[4+j] = b;
            }

            // ih gate pre-activations -> ring slot (zero-init; same order)
            f32x4* ring = &sgx[slot][lane][0];     // one base, offsets 0..80
            #pragma unroll
            for (int tp = 0; tp < 2; ++tp) {
                f32x4 acc = {0.f,0.f,0.f,0.f};
                acc = MFMA(WgH[tp], pH, acc, 0,0,0);
                acc = MFMA(WgH[tp], pL, acc, 0,0,0);
                acc = MFMA(WgL[tp], pH, acc, 0,0,0);
                ring[tp] = acc;
                f32x4 az = {0.f,0.f,0.f,0.f};
                az = MFMA(WgH[2+tp], pH, az, 0,0,0);
                az = MFMA(WgH[2+tp], pL, az, 0,0,0);
                az = MFMA(WgL[2+tp], pH, az, 0,0,0);
                ring[2+tp] = az;
                f32x4 an = {0.f,0.f,0.f,0.f};
                an = MFMA(WgH[4+tp], pH, an, 0,0,0);
                an = MFMA(WgH[4+tp], pL, an, 0,0,0);
                an = MFMA(WgL[4+tp], pH, an, 0,0,0);
                ring[4+tp] = an;
            }
        };

        load_x(0);
        int known_cons = 0;
        for (int tb = 0; tb < TT; tb += 4) {
            #pragma unroll
            for (int u = 0; u < 4; ++u) {
                const int t = tb + u;
                // slot u was consumed at step t-4 -> need s_cons >= t-3
                if (t >= 4 && known_cons < t - 3) {
                    do { known_cons = LD_ACQ(&s_cons); } while (known_cons < t - 3);
                }
                produce(t, u);
                if (lane == 0) ST_REL(&s_prod, t + 1);
            }
        }
    } else {
        // ================= CONSUMER =================
        float ho[2][4] = {{0.f,0.f,0.f,0.f},{0.f,0.f,0.f,0.f}};
        int known_prod = 0;

        auto consume = [&](int t, int slot) {       // slot == t&3, literal
            const int par = slot & 1;               // == t&1
            const float* hrow = sh[par] + m * S + 8 * q;
            f32x4 ha = ((const f32x4*)hrow)[0];
            f32x4 hb = ((const f32x4*)hrow)[1];
            bf16x8 hH, hL;
            #pragma unroll
            for (int j = 0; j < 4; ++j) {
                __bf16 a, b;
                split2(ha[j], a, b); hH[j]   = a; hL[j]   = b;
                split2(hb[j], a, b); hH[4+j] = a; hL[4+j] = b;
            }
            const f32x4* ring = &sgx[slot][lane][0];
            f32x4 aR[2], aZ[2], aHn[2], gN[2];
            #pragma unroll
            for (int tp = 0; tp < 2; ++tp) {
                f32x4 acc = ring[tp];                 // = ih terms
                acc = MFMA(WgH[tp], hH, acc, 0,0,0);
                acc = MFMA(WgH[tp], hL, acc, 0,0,0);
                acc = MFMA(WgL[tp], hH, acc, 0,0,0);
                aR[tp] = acc;
                f32x4 az = ring[2+tp];
                az = MFMA(WgH[2+tp], hH, az, 0,0,0);
                az = MFMA(WgH[2+tp], hL, az, 0,0,0);
                az = MFMA(WgL[2+tp], hH, az, 0,0,0);
                aZ[tp] = az;
                gN[tp] = ring[4+tp];
                f32x4 ah = {0.f,0.f,0.f,0.f};
                ah = MFMA(WgH[4+tp], hH, ah, 0,0,0);
                ah = MFMA(WgH[4+tp], hL, ah, 0,0,0);
                ah = MFMA(WgL[4+tp], hH, ah, 0,0,0);
                aHn[tp] = ah;
            }
            // nonlinearity: rcp-based sigmoid/tanh (no f32 divide sequences)
            #pragma unroll
            for (int tp = 0; tp < 2; ++tp) {
                f32x4 hv;
                #pragma unroll
                for (int r = 0; r < 4; ++r) {
                    const float rg = frcp(1.f + __expf(-aR[tp][r]));
                    const float zg = frcp(1.f + __expf(-aZ[tp][r]));
                    const float nv = gN[tp][r] + rg * aHn[tp][r];
                    const float e  = __expf(-2.f * nv);
                    const float ng = 2.f * frcp(1.f + e) - 1.f;      // tanh
                    const float h2 = zg * (ho[tp][r] - ng) + ng;     // (1-z)n + z h
                    ho[tp][r] = h2; hv[r] = h2;
                }
                float* dst = sh[par ^ 1] + m * S + tp * 16 + 4 * q;
                if (tp == 0) {
                    *(f32x4*)dst = hv;
                } else {
                    if (q < 2)       *(f32x4*)dst = hv;     // units 16-23
                    else if (q == 2) dst[0] = hv[0];        // unit 24
                }
            }
        };

        for (int tb = 0; tb < TT; tb += 4) {
            #pragma unroll
            for (int u = 0; u < 4; ++u) {
                const int t = tb + u;
                if (known_prod < t + 1) {
                    do { known_prod = LD_ACQ(&s_prod); } while (known_prod < t + 1);
                }
                consume(t, u);
                if (lane == 0) ST_REL(&s_cons, t + 1);
            }
        }

        // ---- epilogue: out[seq][unit] ----
        float* orow = out + (size_t)(n0 + m) * HH;
        #pragma unroll
        for (int tp = 0; tp < 2; ++tp) {
            #pragma unroll
            for (int r = 0; r < 4; ++r) {
                const int u = tp * 16 + 4 * q + r;
                if (u < HH) orow[u] = ho[tp][r];
            }
        }
    }
}

extern "C" void kernel_launch(void* const* d_in, const int* in_sizes, int n_in,
                              void* d_out, int out_size, void* d_ws, size_t ws_size,
                              hipStream_t stream) {
    const float* x   = (const float*)d_in[0];
    const float* W1  = (const float*)d_in[1];
    const float* b1  = (const float*)d_in[2];
    const float* Wih = (const float*)d_in[3];
    const float* Whh = (const float*)d_in[4];
    const float* bih = (const float*)d_in[5];
    const float* bhh = (const float*)d_in[6];
    float* out = (float*)d_out;

    gru_ring<<<NSEQ / 16, 128, 0, stream>>>(x, W1, b1, Wih, Whh, bih, bhh, out);
}